// Round 4
// baseline (141.963 us; speedup 1.0000x reference)
//
#include <hip/hip_runtime.h>

#define Bn 4096
#define Dn 66
#define Hn 512

typedef __attribute__((ext_vector_type(8))) short short8;
typedef __attribute__((ext_vector_type(4))) float f32x4;

__device__ __forceinline__ unsigned short f2bf(float x) {
    union { float f; unsigned u; } v; v.f = x;
    unsigned r = v.u + 0x7fffu + ((v.u >> 16) & 1u);   // RNE
    return (unsigned short)(r >> 16);
}
__device__ __forceinline__ float bf2f(unsigned short h) {
    union { float f; unsigned u; } v; v.u = ((unsigned)h) << 16; return v.f;
}

// ============ stage 1: fused prep (cmat, packW2, packW3) + h1/s1' compute ============
// blocks 0..255   : h1 rows r0=bid*16 (fp32 K=67 GEMM), write h1hi/h1lo/s1 bf16 row-major
// blocks 256..383 : CmT[c][a] = bf16(W2[a,c] * sum_i W3[c,i]*W1[i,a]), 4 cols/block
// blocks 384..399 : W2T bf16 transpose via LDS, 4 64x64 tiles/block
// blocks 400..404 : W3T bf16 transpose (padded to 80 rows), 16 j-rows/block
__global__ __launch_bounds__(512, 4) void k_prep_h1(
    const float* __restrict__ xs, const float* __restrict__ tt,
    const float* __restrict__ W1, const float* __restrict__ b1,
    const float* __restrict__ W2, const float* __restrict__ W3,
    unsigned short* __restrict__ W2T, unsigned short* __restrict__ CmT,
    unsigned short* __restrict__ W3T,
    unsigned short* __restrict__ h1hi, unsigned short* __restrict__ h1lo,
    unsigned short* __restrict__ s1)
{
    __shared__ float sX[67*16];                 // h1 branch
    __shared__ unsigned short T[64*72];         // packW2 branch
    const int bid = blockIdx.x, tid = threadIdx.x;

    if (bid < 256) {
        const int r0 = bid*16;
        for (int idx = tid; idx < 67*16; idx += 512) {
            const int i = idx >> 4, r = idx & 15;
            sX[idx] = (i < Dn) ? xs[(size_t)(r0+r)*Dn + i] : tt[r0+r];
        }
        __syncthreads();
        const int lane = tid & 63, wv = tid >> 6;
        const int rg = lane & 7, cg = lane >> 3;
        const int cA = wv*64 + cg*4, cB = cA + 32;
        float z[2][8];
        {
            const float4 bA4 = *(const float4*)&b1[cA];
            const float4 bB4 = *(const float4*)&b1[cB];
            const float bb[8] = {bA4.x,bA4.y,bA4.z,bA4.w, bB4.x,bB4.y,bB4.z,bB4.w};
            #pragma unroll
            for (int j = 0; j < 8; ++j) { z[0][j] = bb[j]; z[1][j] = bb[j]; }
        }
        for (int i = 0; i < 67; ++i) {
            const float2 xf = *(const float2*)&sX[i*16 + 2*rg];
            const float4 wA = *(const float4*)&W1[(size_t)i*Hn + cA];
            const float4 wB = *(const float4*)&W1[(size_t)i*Hn + cB];
            const float ww[8] = {wA.x,wA.y,wA.z,wA.w, wB.x,wB.y,wB.z,wB.w};
            #pragma unroll
            for (int j = 0; j < 8; ++j) {
                z[0][j] = fmaf(xf.x, ww[j], z[0][j]);
                z[1][j] = fmaf(xf.y, ww[j], z[1][j]);
            }
        }
        #pragma unroll
        for (int rr = 0; rr < 2; ++rr) {
            const size_t row = r0 + 2*rg + rr;
            #pragma unroll
            for (int grp = 0; grp < 2; ++grp) {
                ushort4 phi, plo, ps;
                unsigned short* PH = (unsigned short*)&phi;
                unsigned short* PL = (unsigned short*)&plo;
                unsigned short* PS = (unsigned short*)&ps;
                #pragma unroll
                for (int j = 0; j < 4; ++j) {
                    const float zv = z[rr][grp*4 + j];
                    const float sg = 1.f / (1.f + __expf(-zv));
                    const float h  = zv * sg;
                    const float sp = sg * (1.f + zv * (1.f - sg));
                    const unsigned short hh = f2bf(h);
                    PH[j] = hh;
                    PL[j] = f2bf(h - bf2f(hh));
                    PS[j] = f2bf(sp);
                }
                const int base = grp ? cB : cA;
                *(ushort4*)&h1hi[row*Hn + base] = phi;
                *(ushort4*)&h1lo[row*Hn + base] = plo;
                *(ushort4*)&s1  [row*Hn + base] = ps;
            }
        }
    } else if (bid < 384) {
        const int c0 = (bid - 256)*4, a = tid;
        float m[4] = {0.f, 0.f, 0.f, 0.f};
        for (int i = 0; i < Dn; ++i) {
            const float x = W1[(size_t)i*Hn + a];     // coalesced
            m[0] = fmaf(x, W3[(size_t)(c0+0)*Dn + i], m[0]);   // uniform -> s_load
            m[1] = fmaf(x, W3[(size_t)(c0+1)*Dn + i], m[1]);
            m[2] = fmaf(x, W3[(size_t)(c0+2)*Dn + i], m[2]);
            m[3] = fmaf(x, W3[(size_t)(c0+3)*Dn + i], m[3]);
        }
        const float4 w2 = *(const float4*)&W2[(size_t)a*Hn + c0];
        CmT[(size_t)(c0+0)*Hn + a] = f2bf(w2.x * m[0]);
        CmT[(size_t)(c0+1)*Hn + a] = f2bf(w2.y * m[1]);
        CmT[(size_t)(c0+2)*Hn + a] = f2bf(w2.z * m[2]);
        CmT[(size_t)(c0+3)*Hn + a] = f2bf(w2.w * m[3]);
    } else if (bid < 400) {
        #pragma unroll 1
        for (int sub = 0; sub < 4; ++sub) {
            const int tile = (bid - 384)*4 + sub;
            const int a0 = (tile & 7)*64, c0 = (tile >> 3)*64;
            __syncthreads();
            for (int t2 = tid; t2 < 1024; t2 += 512) {
                const int a = t2 >> 4, cc = t2 & 15;
                const float4 v = *(const float4*)&W2[(size_t)(a0+a)*Hn + c0 + cc*4];
                T[(cc*4+0)*72 + a] = f2bf(v.x);
                T[(cc*4+1)*72 + a] = f2bf(v.y);
                T[(cc*4+2)*72 + a] = f2bf(v.z);
                T[(cc*4+3)*72 + a] = f2bf(v.w);
            }
            __syncthreads();
            if (tid < 256) {
                const int c = tid >> 2, ch = tid & 3;
                short8 q0 = *(const short8*)&T[c*72 + ch*16];
                short8 q1 = *(const short8*)&T[c*72 + ch*16 + 8];
                *(short8*)&W2T[(size_t)(c0+c)*Hn + a0 + ch*16]     = q0;
                *(short8*)&W2T[(size_t)(c0+c)*Hn + a0 + ch*16 + 8] = q1;
            }
        }
    } else {
        const int j = (bid - 400)*16 + (tid >> 5);
        const int c0 = (tid & 31)*16;
        #pragma unroll
        for (int k = 0; k < 16; ++k)
            W3T[(size_t)j*Hn + c0 + k] = (j < Dn) ? f2bf(W3[(size_t)(c0+k)*Dn + j]) : (unsigned short)0;
    }
}

// ============ stage 2: z2 = h1@W2 + b2, v = s1'@Cmat; h2 hi/lo + divergence partials ============
// grid 512: block = (row-tile rt = bid>>1) x (col-half = bid&1); 4 waves x 64 cols.
// A-fragments straight from global (no LDS, no phase barriers).
__global__ __launch_bounds__(256, 2) void k_gemm2(
    const unsigned short* __restrict__ h1hi, const unsigned short* __restrict__ h1lo,
    const unsigned short* __restrict__ s1,
    const unsigned short* __restrict__ W2T, const unsigned short* __restrict__ CmT,
    const float* __restrict__ b2,
    unsigned short* __restrict__ h2hi, unsigned short* __restrict__ h2lo,
    float* __restrict__ dpPart)
{
    __shared__ float sRed[4*16];
    const int tid = threadIdx.x, lane = tid & 63, wv = tid >> 6;
    const int rt = blockIdx.x >> 1, half = blockIdx.x & 1;
    const int r0 = rt*16;
    const int c0 = half*256 + wv*64;
    const int n = lane & 15, kg = lane >> 4;

    f32x4 zac[4], vac[4];
    #pragma unroll
    for (int ti = 0; ti < 4; ++ti) {
        const float bz = b2[c0 + ti*16 + n];
        zac[ti] = (f32x4){bz, bz, bz, bz};
        vac[ti] = (f32x4){0.f, 0.f, 0.f, 0.f};
    }
    #pragma unroll 2
    for (int ks = 0; ks < 16; ++ks) {
        const size_t aoff = (size_t)(r0 + n)*Hn + ks*32 + kg*8;
        const short8 ahi = *(const short8*)&h1hi[aoff];
        const short8 alo = *(const short8*)&h1lo[aoff];
        const short8 as1 = *(const short8*)&s1 [aoff];
        #pragma unroll
        for (int ti = 0; ti < 4; ++ti) {
            const size_t wo = (size_t)(c0 + ti*16 + n)*Hn + ks*32 + kg*8;
            const short8 wf = *(const short8*)&W2T[wo];
            const short8 qf = *(const short8*)&CmT[wo];
            zac[ti] = __builtin_amdgcn_mfma_f32_16x16x32_bf16(ahi, wf, zac[ti], 0, 0, 0);
            zac[ti] = __builtin_amdgcn_mfma_f32_16x16x32_bf16(alo, wf, zac[ti], 0, 0, 0);
            vac[ti] = __builtin_amdgcn_mfma_f32_16x16x32_bf16(as1, qf, vac[ti], 0, 0, 0);
        }
    }
    float dp[4] = {0.f, 0.f, 0.f, 0.f};
    #pragma unroll
    for (int ti = 0; ti < 4; ++ti) {
        #pragma unroll
        for (int q = 0; q < 4; ++q) {
            const float z2 = zac[ti][q];
            const float sg = 1.f / (1.f + __expf(-z2));
            const float h2 = z2 * sg;
            dp[q] = fmaf(sg * (1.f + z2 * (1.f - sg)), vac[ti][q], dp[q]);
            const unsigned short hh = f2bf(h2);
            const size_t o = (size_t)(r0 + kg*4 + q)*Hn + c0 + ti*16 + n;
            h2hi[o] = hh;
            h2lo[o] = f2bf(h2 - bf2f(hh));
        }
    }
    #pragma unroll
    for (int q = 0; q < 4; ++q) {
        float v = dp[q];
        v += __shfl_xor(v, 1, 64);
        v += __shfl_xor(v, 2, 64);
        v += __shfl_xor(v, 4, 64);
        v += __shfl_xor(v, 8, 64);
        if (n == 0) sRed[wv*16 + kg*4 + q] = v;
    }
    __syncthreads();
    if (tid < 16) {
        const float s = sRed[tid] + sRed[16+tid] + sRed[32+tid] + sRed[48+tid];
        dpPart[half*Bn + r0 + tid] = s;
    }
}

// ============ stage 3: out = h2@W3 + b3 (split hi/lo) + divergence finalize ============
// 1280 one-wave blocks: rt = bid/5 (16 rows), jt = bid%5 (16 output cols, padded to 80).
__global__ __launch_bounds__(64, 2) void k_gemm3(
    const unsigned short* __restrict__ h2hi, const unsigned short* __restrict__ h2lo,
    const unsigned short* __restrict__ W3T, const float* __restrict__ b3,
    const float* __restrict__ dpPart, float* __restrict__ out)
{
    const int lane = threadIdx.x;
    const int rt = blockIdx.x / 5, jt = blockIdx.x % 5;
    const int r0 = rt*16;
    const int n = lane & 15, kg = lane >> 4;
    const int j = jt*16 + n;
    const float bj = (j < Dn) ? b3[j] : 0.f;
    f32x4 oac = (f32x4){bj, bj, bj, bj};
    #pragma unroll 4
    for (int ks = 0; ks < 16; ++ks) {
        const size_t aoff = (size_t)(r0 + n)*Hn + ks*32 + kg*8;
        const short8 ahi = *(const short8*)&h2hi[aoff];
        const short8 alo = *(const short8*)&h2lo[aoff];
        const short8 wf  = *(const short8*)&W3T[(size_t)j*Hn + ks*32 + kg*8];
        oac = __builtin_amdgcn_mfma_f32_16x16x32_bf16(ahi, wf, oac, 0, 0, 0);
        oac = __builtin_amdgcn_mfma_f32_16x16x32_bf16(alo, wf, oac, 0, 0, 0);
    }
    if (j < Dn) {
        #pragma unroll
        for (int q = 0; q < 4; ++q)
            out[(size_t)(r0 + kg*4 + q)*Dn + j] = oac[q];
    }
    if (jt == 0 && lane < 16)
        out[(size_t)Bn*Dn + r0 + lane] = -(dpPart[r0 + lane] + dpPart[Bn + r0 + lane]);
}

extern "C" void kernel_launch(void* const* d_in, const int* in_sizes, int n_in,
                              void* d_out, int out_size, void* d_ws, size_t ws_size,
                              hipStream_t stream)
{
    const float* xs = (const float*)d_in[0];
    const float* t  = (const float*)d_in[1];
    const float* W1 = (const float*)d_in[2];
    const float* b1 = (const float*)d_in[3];
    const float* W2 = (const float*)d_in[4];
    const float* b2 = (const float*)d_in[5];
    const float* W3 = (const float*)d_in[6];
    const float* b3 = (const float*)d_in[7];
    float* out = (float*)d_out;

    char* ws = (char*)d_ws;
    unsigned short* W2T  = (unsigned short*)(ws);                    // 512 KB
    unsigned short* CmT  = (unsigned short*)(ws + 524288);           // 512 KB
    unsigned short* W3T  = (unsigned short*)(ws + 1048576);          // 80 KB
    unsigned short* h1hi = (unsigned short*)(ws + 1130496);          // 4 MB
    unsigned short* h1lo = (unsigned short*)(ws + 5324800);          // 4 MB
    unsigned short* s1   = (unsigned short*)(ws + 9519104);          // 4 MB
    unsigned short* h2hi = (unsigned short*)(ws + 13713408);         // 4 MB
    unsigned short* h2lo = (unsigned short*)(ws + 17907712);         // 4 MB
    float*          dpP  = (float*)(ws + 22102016);                  // 32 KB

    k_prep_h1<<<405, 512, 0, stream>>>(xs, t, W1, b1, W2, W3, W2T, CmT, W3T, h1hi, h1lo, s1);
    k_gemm2  <<<512, 256, 0, stream>>>(h1hi, h1lo, s1, W2T, CmT, b2, h2hi, h2lo, dpP);
    k_gemm3  <<<1280, 64, 0, stream>>>(h2hi, h2lo, W3T, b3, dpP, out);
}

// Round 5
// 125.233 us; speedup vs baseline: 1.1336x; 1.1336x over previous
//
#include <hip/hip_runtime.h>

#define Bn 4096
#define Dn 66
#define Hn 512

typedef __attribute__((ext_vector_type(8))) short short8;
typedef __attribute__((ext_vector_type(4))) float f32x4;

__device__ __forceinline__ unsigned short f2bf(float x) {
    union { float f; unsigned u; } v; v.f = x;
    unsigned r = v.u + 0x7fffu + ((v.u >> 16) & 1u);   // RNE
    return (unsigned short)(r >> 16);
}
__device__ __forceinline__ float bf2f(unsigned short h) {
    union { float f; unsigned u; } v; v.u = ((unsigned)h) << 16; return v.f;
}

// Fragment-linear layouts (16x16x32 bf16 MFMA):
//   A-frag tile (rt, ks):  lane l (m=l&15, kg=l>>4) holds A[rt*16+m][ks*32+kg*8+j], j=0..7
//       offset = ((rt*16 + ks)*64 + l)*8 + j            (one 1KB contiguous load per wave)
//   B-frag tile (ct, ks):  lane l (n=l&15, kg=l>>4) holds B[ks*32+kg*8+j][ct*16+n]
//       offset = ((ct*16 + ks)*64 + l)*8 + j

// ============ stage 1: h1/s1' (A-frag layout) + fragment-packed W2P/CmP/W3P ============
// blocks 0..255  : h1 rows rt=bid (fp32 K=67 GEMM); write h1hiP/h1loP/s1P in A-frag order
// blocks 256..319: W2P + CmP pack (8 B-frag tiles per block, 1 per wave)
// blocks 320..329: W3P pack (padded to 80 cols)
__global__ __launch_bounds__(512, 2) void k_prep(
    const float* __restrict__ xs, const float* __restrict__ tt,
    const float* __restrict__ W1, const float* __restrict__ b1,
    const float* __restrict__ W2, const float* __restrict__ W3,
    unsigned short* __restrict__ W2P, unsigned short* __restrict__ CmP,
    unsigned short* __restrict__ W3P,
    unsigned short* __restrict__ h1hiP, unsigned short* __restrict__ h1loP,
    unsigned short* __restrict__ s1P)
{
    __shared__ float sX[67*16];
    const int bid = blockIdx.x, tid = threadIdx.x;
    const int lane = tid & 63, wv = tid >> 6;

    if (bid < 256) {
        const int rt = bid, r0 = rt*16;
        for (int idx = tid; idx < 67*16; idx += 512) {
            const int i = idx >> 4, r = idx & 15;
            sX[idx] = (i < Dn) ? xs[(size_t)(r0+r)*Dn + i] : tt[r0+r];
        }
        __syncthreads();
        const int rg = lane & 7, cg = lane >> 3;
        const int cA = wv*64 + cg*4, cB = cA + 32;
        float z[2][8];
        {
            const float4 bA4 = *(const float4*)&b1[cA];
            const float4 bB4 = *(const float4*)&b1[cB];
            const float bb[8] = {bA4.x,bA4.y,bA4.z,bA4.w, bB4.x,bB4.y,bB4.z,bB4.w};
            #pragma unroll
            for (int j = 0; j < 8; ++j) { z[0][j] = bb[j]; z[1][j] = bb[j]; }
        }
        for (int i = 0; i < 67; ++i) {
            const float2 xf = *(const float2*)&sX[i*16 + 2*rg];
            const float4 wA = *(const float4*)&W1[(size_t)i*Hn + cA];
            const float4 wB = *(const float4*)&W1[(size_t)i*Hn + cB];
            const float ww[8] = {wA.x,wA.y,wA.z,wA.w, wB.x,wB.y,wB.z,wB.w};
            #pragma unroll
            for (int j = 0; j < 8; ++j) {
                z[0][j] = fmaf(xf.x, ww[j], z[0][j]);
                z[1][j] = fmaf(xf.y, ww[j], z[1][j]);
            }
        }
        // A-frag stores: 4-col group (cg&1 half of an 8-chunk), kg = cg>>1, ks = 2*wv + grp
        const int kgrp = cg >> 1, joff = (cg & 1)*4;
        #pragma unroll
        for (int rr = 0; rr < 2; ++rr) {
            const int r = 2*rg + rr;
            #pragma unroll
            for (int grp = 0; grp < 2; ++grp) {
                ushort4 phi, plo, ps;
                unsigned short* PH = (unsigned short*)&phi;
                unsigned short* PL = (unsigned short*)&plo;
                unsigned short* PS = (unsigned short*)&ps;
                #pragma unroll
                for (int j = 0; j < 4; ++j) {
                    const float zv = z[rr][grp*4 + j];
                    const float sg = 1.f / (1.f + __expf(-zv));
                    const float h  = zv * sg;
                    const float sp = sg * (1.f + zv * (1.f - sg));
                    const unsigned short hh = f2bf(h);
                    PH[j] = hh;
                    PL[j] = f2bf(h - bf2f(hh));
                    PS[j] = f2bf(sp);
                }
                const int ks = 2*wv + grp;
                const size_t off = ((size_t)(rt*16 + ks)*64 + r + 16*kgrp)*8 + joff;
                *(ushort4*)&h1hiP[off] = phi;
                *(ushort4*)&h1loP[off] = plo;
                *(ushort4*)&s1P [off] = ps;
            }
        }
    } else if (bid < 320) {
        // one B-frag tile per wave: tix = ct*16 + ks
        const int tix = (bid - 256)*8 + wv;
        const int ks = tix & 15;
        const int n = lane & 15, kg = lane >> 4;
        const int c = (tix >> 4)*16 + n;
        const int abase = ks*32 + kg*8;
        float w2v[8], m[8];
        #pragma unroll
        for (int j = 0; j < 8; ++j) {
            w2v[j] = W2[(size_t)(abase + j)*Hn + c];
            m[j] = 0.f;
        }
        for (int i = 0; i < Dn; ++i) {
            const float w3 = W3[(size_t)c*Dn + i];
            const float4 w1a = *(const float4*)&W1[(size_t)i*Hn + abase];
            const float4 w1b = *(const float4*)&W1[(size_t)i*Hn + abase + 4];
            m[0] = fmaf(w3, w1a.x, m[0]); m[1] = fmaf(w3, w1a.y, m[1]);
            m[2] = fmaf(w3, w1a.z, m[2]); m[3] = fmaf(w3, w1a.w, m[3]);
            m[4] = fmaf(w3, w1b.x, m[4]); m[5] = fmaf(w3, w1b.y, m[5]);
            m[6] = fmaf(w3, w1b.z, m[6]); m[7] = fmaf(w3, w1b.w, m[7]);
        }
        short8 pw, pc;
        #pragma unroll
        for (int j = 0; j < 8; ++j) {
            pw[j] = (short)f2bf(w2v[j]);
            pc[j] = (short)f2bf(w2v[j] * m[j]);
        }
        const size_t off = ((size_t)tix*64 + lane)*8;
        *(short8*)&W2P[off] = pw;
        *(short8*)&CmP[off] = pc;
    } else {
        const int tix = (bid - 320)*8 + wv;   // jt*16 + ks, 80 tiles
        if (tix < 80) {
            const int ks = tix & 15;
            const int n = lane & 15, kg = lane >> 4;
            const int j_out = (tix >> 4)*16 + n;
            const int abase = ks*32 + kg*8;
            short8 p;
            #pragma unroll
            for (int j = 0; j < 8; ++j)
                p[j] = (j_out < Dn) ? (short)f2bf(W3[(size_t)(abase + j)*Dn + j_out]) : (short)0;
            *(short8*)&W3P[((size_t)tix*64 + lane)*8] = p;
        }
    }
}

// ============ stage 2: z2 = h1@W2 + b2, v = s1'@Cmat; h2 (A-frag) + divergence partials ====
// grid 512 = 256 row-tiles x 2 col-halves; 4 waves x 64 cols; all loads 1KB coalesced.
__global__ __launch_bounds__(256, 2) void k_gemm2(
    const unsigned short* __restrict__ h1hiP, const unsigned short* __restrict__ h1loP,
    const unsigned short* __restrict__ s1P,
    const unsigned short* __restrict__ W2P, const unsigned short* __restrict__ CmP,
    const float* __restrict__ b2,
    unsigned short* __restrict__ h2hiP, unsigned short* __restrict__ h2loP,
    float* __restrict__ dpPart)
{
    __shared__ float sRed[4*16];
    const int tid = threadIdx.x, lane = tid & 63, wv = tid >> 6;
    const int rt = blockIdx.x >> 1, half = blockIdx.x & 1;
    const int ctb = half*16 + wv*4;          // base ctile; cols [ctb*16, ctb*16+64)
    const int n = lane & 15, kg = lane >> 4;

    f32x4 zac[4], vac[4];
    #pragma unroll
    for (int ti = 0; ti < 4; ++ti) {
        const float bz = b2[(ctb + ti)*16 + n];
        zac[ti] = (f32x4){bz, bz, bz, bz};
        vac[ti] = (f32x4){0.f, 0.f, 0.f, 0.f};
    }
    #pragma unroll 2
    for (int ks = 0; ks < 16; ++ks) {
        const size_t aoff = ((size_t)(rt*16 + ks)*64 + lane)*8;
        const short8 ahi = *(const short8*)&h1hiP[aoff];
        const short8 alo = *(const short8*)&h1loP[aoff];
        const short8 as1 = *(const short8*)&s1P [aoff];
        #pragma unroll
        for (int ti = 0; ti < 4; ++ti) {
            const size_t wo = ((size_t)((ctb + ti)*16 + ks)*64 + lane)*8;
            const short8 wf = *(const short8*)&W2P[wo];
            const short8 qf = *(const short8*)&CmP[wo];
            zac[ti] = __builtin_amdgcn_mfma_f32_16x16x32_bf16(ahi, wf, zac[ti], 0, 0, 0);
            zac[ti] = __builtin_amdgcn_mfma_f32_16x16x32_bf16(alo, wf, zac[ti], 0, 0, 0);
            vac[ti] = __builtin_amdgcn_mfma_f32_16x16x32_bf16(as1, qf, vac[ti], 0, 0, 0);
        }
    }
    float dp[4] = {0.f, 0.f, 0.f, 0.f};
    #pragma unroll
    for (int ti = 0; ti < 4; ++ti) {
        const int c = (ctb + ti)*16 + n;
        const int ks2 = c >> 5, kg2 = (c >> 3) & 3, j2 = c & 7;
        #pragma unroll
        for (int q = 0; q < 4; ++q) {
            const float z2 = zac[ti][q];
            const float sg = 1.f / (1.f + __expf(-z2));
            const float h2 = z2 * sg;
            dp[q] = fmaf(sg * (1.f + z2 * (1.f - sg)), vac[ti][q], dp[q]);
            const unsigned short hh = f2bf(h2);
            const size_t o = ((size_t)(rt*16 + ks2)*64 + (kg*4 + q) + 16*kg2)*8 + j2;
            h2hiP[o] = hh;
            h2loP[o] = f2bf(h2 - bf2f(hh));
        }
    }
    #pragma unroll
    for (int q = 0; q < 4; ++q) {
        float v = dp[q];
        v += __shfl_xor(v, 1, 64);
        v += __shfl_xor(v, 2, 64);
        v += __shfl_xor(v, 4, 64);
        v += __shfl_xor(v, 8, 64);
        if (n == 0) sRed[wv*16 + kg*4 + q] = v;
    }
    __syncthreads();
    if (tid < 16) {
        const float s = sRed[tid] + sRed[16+tid] + sRed[32+tid] + sRed[48+tid];
        dpPart[half*Bn + rt*16 + tid] = s;
    }
}

// ============ stage 3: out = h2@W3 + b3 (hi/lo) + divergence finalize ============
// 1280 one-wave blocks: rt = bid/5, jt = bid%5; all loads coalesced from frag layouts.
__global__ __launch_bounds__(64, 2) void k_gemm3(
    const unsigned short* __restrict__ h2hiP, const unsigned short* __restrict__ h2loP,
    const unsigned short* __restrict__ W3P, const float* __restrict__ b3,
    const float* __restrict__ dpPart, float* __restrict__ out)
{
    const int lane = threadIdx.x;
    const int rt = blockIdx.x / 5, jt = blockIdx.x % 5;
    const int r0 = rt*16;
    const int n = lane & 15, kg = lane >> 4;
    const int j = jt*16 + n;
    const float bj = (j < Dn) ? b3[j] : 0.f;
    f32x4 oac = (f32x4){bj, bj, bj, bj};
    #pragma unroll 4
    for (int ks = 0; ks < 16; ++ks) {
        const size_t aoff = ((size_t)(rt*16 + ks)*64 + lane)*8;
        const short8 ahi = *(const short8*)&h2hiP[aoff];
        const short8 alo = *(const short8*)&h2loP[aoff];
        const short8 wf  = *(const short8*)&W3P[((size_t)(jt*16 + ks)*64 + lane)*8];
        oac = __builtin_amdgcn_mfma_f32_16x16x32_bf16(ahi, wf, oac, 0, 0, 0);
        oac = __builtin_amdgcn_mfma_f32_16x16x32_bf16(alo, wf, oac, 0, 0, 0);
    }
    if (j < Dn) {
        #pragma unroll
        for (int q = 0; q < 4; ++q)
            out[(size_t)(r0 + kg*4 + q)*Dn + j] = oac[q];
    }
    if (jt == 0 && lane < 16)
        out[(size_t)Bn*Dn + r0 + lane] = -(dpPart[r0 + lane] + dpPart[Bn + r0 + lane]);
}

extern "C" void kernel_launch(void* const* d_in, const int* in_sizes, int n_in,
                              void* d_out, int out_size, void* d_ws, size_t ws_size,
                              hipStream_t stream)
{
    const float* xs = (const float*)d_in[0];
    const float* t  = (const float*)d_in[1];
    const float* W1 = (const float*)d_in[2];
    const float* b1 = (const float*)d_in[3];
    const float* W2 = (const float*)d_in[4];
    const float* b2 = (const float*)d_in[5];
    const float* W3 = (const float*)d_in[6];
    const float* b3 = (const float*)d_in[7];
    float* out = (float*)d_out;

    char* ws = (char*)d_ws;
    unsigned short* W2P  = (unsigned short*)(ws);                    // 512 KB
    unsigned short* CmP  = (unsigned short*)(ws + 524288);           // 512 KB
    unsigned short* W3P  = (unsigned short*)(ws + 1048576);          // 80 KB
    unsigned short* h1hi = (unsigned short*)(ws + 1130496);          // 4 MB
    unsigned short* h1lo = (unsigned short*)(ws + 5324800);          // 4 MB
    unsigned short* s1   = (unsigned short*)(ws + 9519104);          // 4 MB
    unsigned short* h2hi = (unsigned short*)(ws + 13713408);         // 4 MB
    unsigned short* h2lo = (unsigned short*)(ws + 17907712);         // 4 MB
    float*          dpP  = (float*)(ws + 22102016);                  // 32 KB

    k_prep <<<330, 512, 0, stream>>>(xs, t, W1, b1, W2, W3, W2P, CmP, W3P, h1hi, h1lo, s1);
    k_gemm2<<<512, 256, 0, stream>>>(h1hi, h1lo, s1, W2P, CmP, b2, h2hi, h2lo, dpP);
    k_gemm3<<<1280, 64, 0, stream>>>(h2hi, h2lo, W3P, b3, dpP, out);
}